// Round 15
// baseline (209.452 us; speedup 1.0000x reference)
//
#include <hip/hip_runtime.h>
#include <hip/hip_bf16.h>

// Problem constants (B=1)
#define T_ 8
#define H_ 64
#define W_ 64
#define C_ 64
#define HW_ (H_ * W_)          // 4096
#define THW_ (T_ * H_ * W_)    // 32768
#define KTAPS 27
#define KDIM (C_ * KTAPS)      // 1728
#define NOFF 54
#define OSTR 58                // LDS offsets panel stride (floats)
#define RSTR 20                // LDS reduction stride (floats; 80B = 16B-aligned, 2-way banks)

typedef __bf16 bf16x8 __attribute__((ext_vector_type(8)));
typedef float floatx4 __attribute__((ext_vector_type(4)));

// ---------------------------------------------------------------------------
// prep + to_cl merged: one launch, disjoint outputs.
//  ws[tap*4096 + g16*1024 + s*512 + lane*8 + j]
//    = W[co = g16*16 + (lane&15)][cin = s*32 + (lane>>4)*8 + j][tap]
// ---------------------------------------------------------------------------
__global__ __launch_bounds__(256) void prep_tocl_kernel(
    const float* __restrict__ x, __hip_bfloat16* __restrict__ xcl,
    const float* __restrict__ w1, const float* __restrict__ woff,
    const float* __restrict__ wd, const float* __restrict__ wr,
    __hip_bfloat16* __restrict__ w1s, __hip_bfloat16* __restrict__ woffs,
    __hip_bfloat16* __restrict__ wds, __hip_bfloat16* __restrict__ wrs) {
    __shared__ float tile[64][65];
    const int tid = threadIdx.x;

    {
        int i = blockIdx.x * 256 + tid;
        if (i < C_ * KDIM) {
            int j = i & 7, lane = (i >> 3) & 63, s = (i >> 9) & 1, g16 = (i >> 10) & 3, tap = i >> 12;
            int co = g16 * 16 + (lane & 15);
            int cin = s * 32 + (lane >> 4) * 8 + j;
            int src = (co * C_ + cin) * KTAPS + tap;
            w1s[i] = __float2bfloat16(w1[src]);
            woffs[i] = (co < NOFF) ? __float2bfloat16(woff[src]) : __float2bfloat16(0.f);
            wds[i] = __float2bfloat16(wd[src]);
        }
        if (i < C_ * C_) {
            int j = i & 7, lane = (i >> 3) & 63, s = (i >> 9) & 1, g16 = i >> 10;
            int co = g16 * 16 + (lane & 15);
            int cin = s * 32 + (lane >> 4) * 8 + j;
            wrs[i] = __float2bfloat16(wr[co * C_ + cin]);
        }
    }

    const int pos0 = blockIdx.x * 64;
    for (int i = tid; i < 4096; i += 256) {
        int ch = i >> 6, p = i & 63;
        tile[ch][p] = x[ch * THW_ + pos0 + p];
    }
    __syncthreads();
    for (int i = tid; i < 4096; i += 256) {
        int p = i >> 6, ch = i & 63;
        xcl[(pos0 + p) * C_ + ch] = __float2bfloat16(tile[ch][p]);
    }
}

// ---------------------------------------------------------------------------
// BARRIER-FREE per-wave streaming MFMA 3x3x3 conv (conv1) — R12 form.
// ---------------------------------------------------------------------------
__global__ __launch_bounds__(256) void conv_stream_kernel(
    const __hip_bfloat16* __restrict__ in_cl,
    const __hip_bfloat16* __restrict__ wTs,   // swizzled (27*4096)
    const float* __restrict__ bias,
    __hip_bfloat16* __restrict__ out_cl_b16) {
    __shared__ __hip_bfloat16 ts[32 * 72];    // 4608B bounce

    const int tid = threadIdx.x;
    const int wv = tid >> 6;
    const int lane = tid & 63;
    const int l15 = lane & 15;
    const int quad = lane >> 4;
    const int wh = blockIdx.x & 1;
    const int h = (blockIdx.x >> 1) & 63;
    const int t = blockIdx.x >> 7;
    const int w0 = wh * 32;
    const int pg = wv >> 1;
    const int chf = wv & 1;
    const int wpos = w0 + pg * 16 + l15;
    const int posbase = t * HW_ + h * W_;

    floatx4 acc0 = (floatx4){0.f, 0.f, 0.f, 0.f};
    floatx4 acc1 = (floatx4){0.f, 0.f, 0.f, 0.f};
    const bf16x8 z = {};
    const __hip_bfloat16* wb = wTs + chf * 2048 + lane * 8;

    const int ktlo = (t == 0) ? 1 : 0;
    const int kthi = (t == T_ - 1) ? 2 : 3;

    for (int kt = ktlo; kt < kthi; ++kt) {
        const int t_in = t - 1 + kt;
#pragma unroll 1
        for (int kh = 0; kh < 3; ++kh) {
            const int h_in = h - 1 + kh;
            if ((unsigned)h_in >= H_) continue;
            const int rowbase = t_in * HW_ + h_in * W_;
#pragma unroll
            for (int kw = 0; kw < 3; ++kw) {
                const int tap = kt * 9 + kh * 3 + kw;
                const int w_in = wpos - 1 + kw;
                const bool v = (unsigned)w_in < W_;
                const int wc = v ? w_in : 0;
                const __hip_bfloat16* ap = in_cl + (rowbase + wc) * C_ + quad * 8;
                bf16x8 a0 = *(const bf16x8*)(ap);
                bf16x8 a1 = *(const bf16x8*)(ap + 32);
                a0 = v ? a0 : z;
                a1 = v ? a1 : z;
                const __hip_bfloat16* bp = wb + tap * 4096;
                const bf16x8 b00 = *(const bf16x8*)(bp);
                const bf16x8 b01 = *(const bf16x8*)(bp + 512);
                const bf16x8 b10 = *(const bf16x8*)(bp + 1024);
                const bf16x8 b11 = *(const bf16x8*)(bp + 1536);
                acc0 = __builtin_amdgcn_mfma_f32_16x16x32_bf16(a0, b00, acc0, 0, 0, 0);
                acc0 = __builtin_amdgcn_mfma_f32_16x16x32_bf16(a1, b01, acc0, 0, 0, 0);
                acc1 = __builtin_amdgcn_mfma_f32_16x16x32_bf16(a0, b10, acc1, 0, 0, 0);
                acc1 = __builtin_amdgcn_mfma_f32_16x16x32_bf16(a1, b11, acc1, 0, 0, 0);
            }
        }
    }

    const int n0 = chf * 32 + l15;
    const float bv0 = bias[n0], bv1 = bias[n0 + 16];
#pragma unroll
    for (int r = 0; r < 4; ++r) {
        const int p = pg * 16 + quad * 4 + r;
        float v0 = acc0[r] + bv0;
        v0 = (v0 >= 0.f) ? v0 : 0.01f * v0;
        float v1 = acc1[r] + bv1;
        v1 = (v1 >= 0.f) ? v1 : 0.01f * v1;
        ts[p * 72 + n0] = __float2bfloat16(v0);
        ts[p * 72 + n0 + 16] = __float2bfloat16(v1);
    }
    __syncthreads();
    {
        const int p = tid >> 3, ck = tid & 7;
        const uint4 v4 = *(const uint4*)&ts[p * 72 + ck * 8];
        *(uint4*)&out_cl_b16[(posbase + w0 + p) * C_ + ck * 8] = v4;
    }
}

// ---------------------------------------------------------------------------
// FUSED offsets-conv + BARRIER-FREE K-SPLIT deformable conv + residual (R15).
//  Block = (t,h,w-half): 32 pos, 4 waves, grid T*H*2 = 1024 (16 waves/CU).
//  Phase 1 (R12-proven): wave = 16 pos x 32 co offsets conv -> offs[32][58].
//  Phase 2: wave (pg, ks) = 16 pos x 64 co x CIN-HALF ks:
//   - gather 4x16B corners at channels quad*8 + ks*32 (each byte loaded once
//     per block -> no R10-style duplication), blend 8 ch, 4 MFMAs (s=ks slice).
//   - barrier-free 2-deep named gA/gB pipeline (R14's win) at 2x the waves.
//   - fp32 reduction: ks=1 writes acc to padded LDS, ks=0 adds + lrelu +
//     residual (computed whole by ks=0) + store. One barrier.
// ---------------------------------------------------------------------------
struct Gath {
    bf16x8 c00, c01, c10, c11;
    float w00, w01, w10, w11;
};

__global__ __launch_bounds__(256) void deform_fused_kernel(
    const __hip_bfloat16* __restrict__ y1b,
    const __hip_bfloat16* __restrict__ woffs, const float* __restrict__ boff,
    const __hip_bfloat16* __restrict__ wds, const float* __restrict__ bd,
    const __hip_bfloat16* __restrict__ xclb, const __hip_bfloat16* __restrict__ wrs,
    const float* __restrict__ br, float* __restrict__ out) {
    __shared__ float offs[32 * OSTR];        // 7424 B
    __shared__ float red[128 * RSTR];        // 10240 B

    const int tid = threadIdx.x;
    const int wv = tid >> 6;
    const int lane = tid & 63;
    const int l15 = lane & 15;
    const int quad = lane >> 4;
    const int wh = blockIdx.x & 1;
    const int h = (blockIdx.x >> 1) & 63;
    const int t = blockIdx.x >> 7;
    const int w0 = wh * 32;
    const int posbase = t * HW_ + h * W_;
    const int pg = wv >> 1;                  // position group (16 pos)
    const int ks = wv & 1;                   // cin half
    const int wpos = w0 + pg * 16 + l15;     // this lane's position (A row)
    const int mypos = posbase + wpos;

    // ================= Phase 1: offsets conv -> LDS (R12 form) =================
    {
        floatx4 oa0 = (floatx4){0.f, 0.f, 0.f, 0.f};
        floatx4 oa1 = (floatx4){0.f, 0.f, 0.f, 0.f};
        const bf16x8 z = {};
        const __hip_bfloat16* wb = woffs + ks * 2048 + lane * 8;  // chf == ks slot
        const int ktlo = (t == 0) ? 1 : 0;
        const int kthi = (t == T_ - 1) ? 2 : 3;

        for (int kt = ktlo; kt < kthi; ++kt) {
            const int t_in = t - 1 + kt;
#pragma unroll 1
            for (int kh = 0; kh < 3; ++kh) {
                const int h_in = h - 1 + kh;
                if ((unsigned)h_in >= H_) continue;
                const int rowbase = t_in * HW_ + h_in * W_;
#pragma unroll
                for (int kw = 0; kw < 3; ++kw) {
                    const int tap = kt * 9 + kh * 3 + kw;
                    const int w_in = wpos - 1 + kw;
                    const bool v = (unsigned)w_in < W_;
                    const int wc = v ? w_in : 0;
                    const __hip_bfloat16* ap = y1b + (rowbase + wc) * C_ + quad * 8;
                    bf16x8 a0 = *(const bf16x8*)(ap);
                    bf16x8 a1 = *(const bf16x8*)(ap + 32);
                    a0 = v ? a0 : z;
                    a1 = v ? a1 : z;
                    const __hip_bfloat16* bp = wb + tap * 4096;
                    const bf16x8 b00 = *(const bf16x8*)(bp);
                    const bf16x8 b01 = *(const bf16x8*)(bp + 512);
                    const bf16x8 b10 = *(const bf16x8*)(bp + 1024);
                    const bf16x8 b11 = *(const bf16x8*)(bp + 1536);
                    oa0 = __builtin_amdgcn_mfma_f32_16x16x32_bf16(a0, b00, oa0, 0, 0, 0);
                    oa0 = __builtin_amdgcn_mfma_f32_16x16x32_bf16(a1, b01, oa0, 0, 0, 0);
                    oa1 = __builtin_amdgcn_mfma_f32_16x16x32_bf16(a0, b10, oa1, 0, 0, 0);
                    oa1 = __builtin_amdgcn_mfma_f32_16x16x32_bf16(a1, b11, oa1, 0, 0, 0);
                }
            }
        }
        // D layout: col(l15)=cout-within-16, row(quad*4+r)=pos-within-16
        const int n0 = ks * 32 + l15;                 // 0..15 or 32..47 (<54)
        const float bv0 = boff[n0];
        const float bv1 = (n0 + 16 < NOFF) ? boff[n0 + 16] : 0.f;
#pragma unroll
        for (int r = 0; r < 4; ++r) {
            const int p = pg * 16 + quad * 4 + r;
            offs[p * OSTR + n0] = oa0[r] + bv0;
            if (n0 + 16 < NOFF) offs[p * OSTR + n0 + 16] = oa1[r] + bv1;
        }
    }
    __syncthreads();

    // ================= Phase 2: barrier-free K-split deform =================
    floatx4 acc[4], racc[4];
#pragma unroll
    for (int j = 0; j < 4; ++j) {
        acc[j] = (floatx4){0.f, 0.f, 0.f, 0.f};
        racc[j] = (floatx4){0.f, 0.f, 0.f, 0.f};
    }

    // residual 1x1 on x: whole K, done by ks==0 waves only (wave-uniform branch)
    if (ks == 0) {
        const __hip_bfloat16* ap = xclb + mypos * C_ + quad * 8;
        const bf16x8 ra0 = *(const bf16x8*)(ap);
        const bf16x8 ra1 = *(const bf16x8*)(ap + 32);
#pragma unroll
        for (int j = 0; j < 4; ++j) {
            const __hip_bfloat16* rp = wrs + j * 1024 + lane * 8;
            racc[j] = __builtin_amdgcn_mfma_f32_16x16x32_bf16(ra0, *(const bf16x8*)(rp), racc[j], 0, 0, 0);
            racc[j] = __builtin_amdgcn_mfma_f32_16x16x32_bf16(ra1, *(const bf16x8*)(rp + 512), racc[j], 0, 0, 0);
        }
    }

    const int k0 = (t == 0) ? 9 : 0;
    const int k1 = (t == T_ - 1) ? 18 : KTAPS;
    const int chb = quad * 8 + ks * 32;      // this wave's channel base

    auto gather = [&](int k, Gath& g) {
        const int kt = k / 9, kh = (k / 3) % 3, kw = k % 3;
        const int t_in = t - 1 + kt;                  // in range by k0/k1
        const float dh = offs[(pg * 16 + l15) * OSTR + 2 * k];
        const float dw = offs[(pg * 16 + l15) * OSTR + 2 * k + 1];
        const float hs = (float)(h - 1 + kh) + dh;
        const float wsv = (float)(wpos - 1 + kw) + dw;
        const float h0f = floorf(hs), w0f = floorf(wsv);
        const float fh = hs - h0f, fw = wsv - w0f;
        const int h0i = (int)h0f, w0i = (int)w0f;
        const int h1i = h0i + 1, w1i = w0i + 1;
        const float m_h0 = ((unsigned)h0i < H_) ? 1.f : 0.f;
        const float m_h1 = ((unsigned)h1i < H_) ? 1.f : 0.f;
        const float m_w0 = ((unsigned)w0i < W_) ? 1.f : 0.f;
        const float m_w1 = ((unsigned)w1i < W_) ? 1.f : 0.f;
        g.w00 = (1.f - fh) * (1.f - fw) * m_h0 * m_w0;
        g.w01 = (1.f - fh) * fw * m_h0 * m_w1;
        g.w10 = fh * (1.f - fw) * m_h1 * m_w0;
        g.w11 = fh * fw * m_h1 * m_w1;
        const int h0c = min(max(h0i, 0), H_ - 1);
        const int h1c = min(max(h1i, 0), H_ - 1);
        const int w0c = min(max(w0i, 0), W_ - 1);
        const int w1c = min(max(w1i, 0), W_ - 1);
        const int tb = t_in * HW_;
        g.c00 = *(const bf16x8*)(y1b + (tb + h0c * W_ + w0c) * C_ + chb);
        g.c01 = *(const bf16x8*)(y1b + (tb + h0c * W_ + w1c) * C_ + chb);
        g.c10 = *(const bf16x8*)(y1b + (tb + h1c * W_ + w0c) * C_ + chb);
        g.c11 = *(const bf16x8*)(y1b + (tb + h1c * W_ + w1c) * C_ + chb);
    };
    auto blend = [&](const Gath& g, bf16x8& o) {
        union U { bf16x8 v; __hip_bfloat16 e[8]; };
        U a00, a01, a10, a11, r;
        a00.v = g.c00; a01.v = g.c01; a10.v = g.c10; a11.v = g.c11;
#pragma unroll
        for (int j = 0; j < 8; ++j) {
            float f = g.w00 * __bfloat162float(a00.e[j]) + g.w01 * __bfloat162float(a01.e[j]) +
                      g.w10 * __bfloat162float(a10.e[j]) + g.w11 * __bfloat162float(a11.e[j]);
            r.e[j] = __float2bfloat16(f);
        }
        o = r.v;
    };
    auto mfma4 = [&](int k, bf16x8 a) {
        const __hip_bfloat16* bp = wds + k * 4096 + ks * 512 + lane * 8;
#pragma unroll
        for (int j = 0; j < 4; ++j)
            acc[j] = __builtin_amdgcn_mfma_f32_16x16x32_bf16(a, *(const bf16x8*)(bp + j * 1024), acc[j], 0, 0, 0);
    };

    // 2-deep named pipeline; no barriers in the tap loop -> loads stay in flight
    Gath gA, gB;
    gather(k0, gA);
    gather(k0 + 1, gB);                       // k1-k0 >= 18, always valid
    int k = k0;
    for (; k + 1 < k1; k += 2) {
        bf16x8 a;
        blend(gA, a);                         // consumes loads issued 2 taps ago
        if (k + 2 < k1) gather(k + 2, gA);
        mfma4(k, a);
        blend(gB, a);
        if (k + 3 < k1) gather(k + 3, gB);
        mfma4(k + 1, a);
    }
    if (k < k1) {                             // tail (27-tap blocks): even kr -> gA
        bf16x8 a;
        blend(gA, a);
        mfma4(k, a);
    }

    // ================= Reduction: accA + accB, epilogue by ks==0 =================
    if (ks == 1) {
        float* rp = &red[(pg * 64 + lane) * RSTR];
#pragma unroll
        for (int j = 0; j < 4; ++j) *(floatx4*)&rp[j * 4] = acc[j];
    }
    __syncthreads();
    if (ks == 0) {
        const float* rp = &red[(pg * 64 + lane) * RSTR];
#pragma unroll
        for (int j = 0; j < 4; ++j) {
            const floatx4 other = *(const floatx4*)&rp[j * 4];
            const int cout = j * 16 + l15;
            const float bdv = bd[cout];
            const float brv = br[cout];
            floatx4 o;
#pragma unroll
            for (int r = 0; r < 4; ++r) {
                float v = acc[j][r] + other[r] + bdv;
                v = (v >= 0.f) ? v : 0.01f * v;
                o[r] = v + racc[j][r] + brv;
            }
            *(floatx4*)&out[cout * THW_ + posbase + w0 + pg * 16 + quad * 4] = o;
        }
    }
}

// ---------------------------------------------------------------------------
extern "C" void kernel_launch(void* const* d_in, const int* in_sizes, int n_in,
                              void* d_out, int out_size, void* d_ws, size_t ws_size,
                              hipStream_t stream) {
    const float* x    = (const float*)d_in[0];
    const float* W1   = (const float*)d_in[1];
    const float* b1   = (const float*)d_in[2];
    const float* Woff = (const float*)d_in[3];
    const float* boff = (const float*)d_in[4];
    const float* Wd   = (const float*)d_in[5];
    const float* bd   = (const float*)d_in[6];
    const float* Wr   = (const float*)d_in[7];
    const float* br   = (const float*)d_in[8];
    float* out = (float*)d_out;

    float* ws = (float*)d_ws;
    __hip_bfloat16* xclb  = (__hip_bfloat16*)(ws);             // 2,097,152 bf16
    __hip_bfloat16* y1b   = (__hip_bfloat16*)(ws + 1048576);   // 2,097,152 bf16
    __hip_bfloat16* w1s   = (__hip_bfloat16*)(ws + 2097152);   //   110,592 bf16
    __hip_bfloat16* woffs = (__hip_bfloat16*)(ws + 2152448);   //   110,592 bf16
    __hip_bfloat16* wdsb  = (__hip_bfloat16*)(ws + 2207744);   //   110,592 bf16
    __hip_bfloat16* wrsb  = (__hip_bfloat16*)(ws + 2263040);   //     4,096 bf16
    // total ~9.1 MB

    prep_tocl_kernel<<<THW_ / 64, 256, 0, stream>>>(
        x, xclb, W1, Woff, Wd, Wr, w1s, woffs, wdsb, wrsb);

    conv_stream_kernel<<<dim3(T_ * H_ * 2), 256, 0, stream>>>(
        xclb, w1s, b1, y1b);

    deform_fused_kernel<<<dim3(T_ * H_ * 2), 256, 0, stream>>>(
        y1b, woffs, boff, wdsb, bd, xclb, wrsb, br, out);
}